// Round 11
// baseline (257.408 us; speedup 1.0000x reference)
//
#include <hip/hip_runtime.h>

// B=4, N=2048, F=1024, H=16, D=64.  All dims hard-coded.
#define LOG2E 1.44269504088896340736f

typedef float f32x4 __attribute__((ext_vector_type(4)));
typedef float f32x16 __attribute__((ext_vector_type(16)));
typedef __bf16 bf16x8 __attribute__((ext_vector_type(8)));

__device__ __forceinline__ unsigned short f2bf(float f){
  unsigned int u = __builtin_bit_cast(unsigned int, f);
  u += 0x7fffu + ((u >> 16) & 1u);          // RNE
  return (unsigned short)(u >> 16);
}

__device__ __forceinline__ void gload_lds16(const void* g, void* l){
  __builtin_amdgcn_global_load_lds(
      (const __attribute__((address_space(1))) unsigned int*)g,
      (__attribute__((address_space(3))) unsigned int*)l, 16, 0, 0);
}

// ---- x (fp32 [8192][1024]) -> bf16, 128B-block swizzled: byte ^= ((row&7)<<4)
__global__ __launch_bounds__(256) void cvt_x(const float* __restrict__ x,
                                             unsigned short* __restrict__ xs){
  int t = blockIdx.x * 256 + threadIdx.x;   // 1,048,576 chunks of 8 elems
  int m = t >> 7, c = t & 127;
  const float4* p = (const float4*)(x + ((size_t)m << 10) + (c << 3));
  float4 f0 = p[0], f1 = p[1];
  unsigned int w0 = f2bf(f0.x) | ((unsigned int)f2bf(f0.y) << 16);
  unsigned int w1 = f2bf(f0.z) | ((unsigned int)f2bf(f0.w) << 16);
  unsigned int w2 = f2bf(f1.x) | ((unsigned int)f2bf(f1.y) << 16);
  unsigned int w3 = f2bf(f1.z) | ((unsigned int)f2bf(f1.w) << 16);
  int byte = (c << 4) ^ ((m & 7) << 4);
  *(uint4*)((char*)xs + ((size_t)m << 11) + byte) = make_uint4(w0, w1, w2, w3);
}

// ---- W (fp32 [1024k][1024n]) -> bf16 transposed Wt[n][k], same swizzle by n
__global__ __launch_bounds__(256) void cvt_w(const float* __restrict__ Wq,
                                             const float* __restrict__ Wk,
                                             const float* __restrict__ Wv,
                                             unsigned short* __restrict__ wtq,
                                             unsigned short* __restrict__ wtk,
                                             unsigned short* __restrict__ wtv){
  int t = blockIdx.x * 256 + threadIdx.x;   // 131072 per matrix
  int n = t & 1023, c = t >> 10;            // c = k-chunk (8 k's)
  const float* W = blockIdx.y == 0 ? Wq : blockIdx.y == 1 ? Wk : Wv;
  unsigned short* o = blockIdx.y == 0 ? wtq : blockIdx.y == 1 ? wtk : wtv;
  unsigned int w[4];
  #pragma unroll
  for (int i = 0; i < 4; ++i){
    float a = W[(size_t)(c * 8 + 2 * i) * 1024 + n];
    float b = W[(size_t)(c * 8 + 2 * i + 1) * 1024 + n];
    w[i] = f2bf(a) | ((unsigned int)f2bf(b) << 16);
  }
  int byte = (c << 4) ^ ((n & 7) << 4);
  *(uint4*)((char*)o + ((size_t)n << 11) + byte) = make_uint4(w[0], w[1], w[2], w[3]);
}

// ---- projection GEMM, 256x256 tile, BK=64, 8 waves (2M x 4N), 8-PHASE
// counted-vmcnt pipeline (T3+T4). Stage source is LINEAR chunk (lane&7): the
// xs/wt storage is ALREADY swizzled by cvt_x/cvt_w, so storage-swz == read-swz
// (Round-7-verified algebra). All slot overwrites are barrier-separated from
// the tenant's last read: ph0->{B1,A1}(w+1) [other-parity slots], ph1->none,
// ph2->B0(w+2), ph3->A0(w+2). Window checkpoint vmcnt(4) (={B0,A0}(w+2) in
// flight), vmcnt(0) for w>=14. LDS = 4 rolling 128-row slots per matrix (128KB).
// Q: scaled by 0.125, [b,h,n,d]. K: [b,h,n,d]. V transposed: [b,h,d,n].
__global__ __launch_bounds__(512, 2) void proj_gemm(
    const unsigned short* __restrict__ xs,
    const unsigned short* __restrict__ wt0, const unsigned short* __restrict__ wt1,
    const unsigned short* __restrict__ wt2,
    const float* __restrict__ b0, const float* __restrict__ b1, const float* __restrict__ b2,
    unsigned short* __restrict__ o0, unsigned short* __restrict__ o1,
    unsigned short* __restrict__ o2){
  __shared__ char AL[4][16384];   // [parity*2+half][128 rows][128 B]
  __shared__ char BL[4][16384];
  const int v = blockIdx.z;
  const unsigned short* wt = v == 0 ? wt0 : v == 1 ? wt1 : wt2;
  const float* bias = v == 0 ? b0 : v == 1 ? b1 : b2;
  const int row0 = blockIdx.x << 8;
  const int col0 = blockIdx.y << 8;
  const int tid = threadIdx.x;
  const int wave = tid >> 6, lane = tid & 63;
  const int wr = wave >> 2, wc = wave & 3;       // 2M x 4N wave grid
  const int l15 = lane & 15, lg = lane >> 4;
  const char* xsb = (const char*)xs;
  const char* wtb = (const char*)wt;

  f32x4 acc[8][4] = {};

#define STAGE_A(slot, kt, half) do {                                          \
  _Pragma("unroll")                                                           \
  for (int j_ = 0; j_ < 2; ++j_){                                             \
    int rh_ = (j_ * 8 + wave) * 8 + (lane >> 3);                              \
    int gr_ = row0 + (half) * 128 + rh_;                                      \
    gload_lds16(xsb + (size_t)gr_ * 2048 + (kt) * 128 + ((lane & 7) << 4),    \
                AL[slot] + (j_ * 8 + wave) * 1024);                           \
  } } while (0)

#define STAGE_B(slot, kt, half) do {                                          \
  _Pragma("unroll")                                                           \
  for (int j_ = 0; j_ < 2; ++j_){                                             \
    int rh_ = (j_ * 8 + wave) * 8 + (lane >> 3);                              \
    int gc_ = col0 + (half) * 128 + rh_;                                      \
    gload_lds16(wtb + (size_t)gc_ * 2048 + (kt) * 128 + ((lane & 7) << 4),    \
                BL[slot] + (j_ * 8 + wave) * 1024);                           \
  } } while (0)

  // prologue: tile0 all 4 halves (8 loads) + {B0,A0}(1) (4 loads); wait tile0.
  STAGE_A(0, 0, 0); STAGE_A(1, 0, 1); STAGE_B(0, 0, 0); STAGE_B(1, 0, 1);
  STAGE_B(2, 1, 0); STAGE_A(2, 1, 0);
  asm volatile("s_waitcnt vmcnt(4)" ::: "memory");
  __builtin_amdgcn_s_barrier();

  const int fb0 = ((lg    ) ^ (l15 & 7)) << 4;   // k-slice 0 chunk byte
  const int fb1 = ((lg + 4) ^ (l15 & 7)) << 4;   // k-slice 1 chunk byte
  const int browB = (wc & 1) << 6;               // wave's 64-row band in B-half

  for (int w = 0; w < 16; ++w){
    const int par  = (w & 1) << 1;
    const int npar = 2 - par;                    // parity slots of w+1
    const char* Asl = AL[par + wr];
    const char* Bsl = BL[par + (wc >> 1)];
    bf16x8 afr[4][2], bfA[2][2], bfB[2][2];

    // -------- phase 0: quadrant (0,0); stage B1(w+1), A1(w+1) --------
    #pragma unroll
    for (int mt = 0; mt < 4; ++mt){
      afr[mt][0] = *(const bf16x8*)(Asl + (mt * 16 + l15) * 128 + fb0);
      afr[mt][1] = *(const bf16x8*)(Asl + (mt * 16 + l15) * 128 + fb1);
    }
    #pragma unroll
    for (int nt = 0; nt < 2; ++nt){
      bfA[nt][0] = *(const bf16x8*)(Bsl + (browB + nt * 16 + l15) * 128 + fb0);
      bfA[nt][1] = *(const bf16x8*)(Bsl + (browB + nt * 16 + l15) * 128 + fb1);
    }
    __builtin_amdgcn_sched_barrier(0);
    if (w + 1 < 16){ STAGE_B(npar + 1, w + 1, 1); STAGE_A(npar + 1, w + 1, 1); }
    __builtin_amdgcn_s_barrier();
    asm volatile("s_waitcnt lgkmcnt(0)" ::: "memory");
    __builtin_amdgcn_sched_barrier(0);
    __builtin_amdgcn_s_setprio(1);
    #pragma unroll
    for (int mt = 0; mt < 4; ++mt)
      #pragma unroll
      for (int nt = 0; nt < 2; ++nt){
        acc[mt][nt] = __builtin_amdgcn_mfma_f32_16x16x32_bf16(afr[mt][0], bfA[nt][0], acc[mt][nt], 0, 0, 0);
        acc[mt][nt] = __builtin_amdgcn_mfma_f32_16x16x32_bf16(afr[mt][1], bfA[nt][1], acc[mt][nt], 0, 0, 0);
      }
    __builtin_amdgcn_s_setprio(0);
    __builtin_amdgcn_s_barrier();

    // -------- phase 1: quadrant (0,1); no stage --------
    #pragma unroll
    for (int nt = 0; nt < 2; ++nt){
      bfB[nt][0] = *(const bf16x8*)(Bsl + (browB + 32 + nt * 16 + l15) * 128 + fb0);
      bfB[nt][1] = *(const bf16x8*)(Bsl + (browB + 32 + nt * 16 + l15) * 128 + fb1);
    }
    __builtin_amdgcn_s_barrier();
    asm volatile("s_waitcnt lgkmcnt(0)" ::: "memory");
    __builtin_amdgcn_sched_barrier(0);
    __builtin_amdgcn_s_setprio(1);
    #pragma unroll
    for (int mt = 0; mt < 4; ++mt)
      #pragma unroll
      for (int nt = 0; nt < 2; ++nt){
        acc[mt][2 + nt] = __builtin_amdgcn_mfma_f32_16x16x32_bf16(afr[mt][0], bfB[nt][0], acc[mt][2 + nt], 0, 0, 0);
        acc[mt][2 + nt] = __builtin_amdgcn_mfma_f32_16x16x32_bf16(afr[mt][1], bfB[nt][1], acc[mt][2 + nt], 0, 0, 0);
      }
    __builtin_amdgcn_s_setprio(0);
    __builtin_amdgcn_s_barrier();

    // -------- phase 2: quadrant (1,0); stage B0(w+2) --------
    #pragma unroll
    for (int mt = 0; mt < 4; ++mt){
      afr[mt][0] = *(const bf16x8*)(Asl + ((64 + mt * 16) + l15) * 128 + fb0);
      afr[mt][1] = *(const bf16x8*)(Asl + ((64 + mt * 16) + l15) * 128 + fb1);
    }
    __builtin_amdgcn_sched_barrier(0);
    if (w + 2 < 16) STAGE_B(par + 0, w + 2, 0);
    __builtin_amdgcn_s_barrier();
    asm volatile("s_waitcnt lgkmcnt(0)" ::: "memory");
    __builtin_amdgcn_sched_barrier(0);
    __builtin_amdgcn_s_setprio(1);
    #pragma unroll
    for (int mt = 0; mt < 4; ++mt)
      #pragma unroll
      for (int nt = 0; nt < 2; ++nt){
        acc[4 + mt][nt] = __builtin_amdgcn_mfma_f32_16x16x32_bf16(afr[mt][0], bfA[nt][0], acc[4 + mt][nt], 0, 0, 0);
        acc[4 + mt][nt] = __builtin_amdgcn_mfma_f32_16x16x32_bf16(afr[mt][1], bfA[nt][1], acc[4 + mt][nt], 0, 0, 0);
      }
    __builtin_amdgcn_s_setprio(0);
    __builtin_amdgcn_s_barrier();

    // -------- phase 3: quadrant (1,1); stage A0(w+2); window checkpoint --------
    if (w + 2 < 16) STAGE_A(par + 0, w + 2, 0);
    __builtin_amdgcn_s_barrier();
    __builtin_amdgcn_s_setprio(1);
    #pragma unroll
    for (int mt = 0; mt < 4; ++mt)
      #pragma unroll
      for (int nt = 0; nt < 2; ++nt){
        acc[4 + mt][2 + nt] = __builtin_amdgcn_mfma_f32_16x16x32_bf16(afr[mt][0], bfB[nt][0], acc[4 + mt][2 + nt], 0, 0, 0);
        acc[4 + mt][2 + nt] = __builtin_amdgcn_mfma_f32_16x16x32_bf16(afr[mt][1], bfB[nt][1], acc[4 + mt][2 + nt], 0, 0, 0);
      }
    __builtin_amdgcn_s_setprio(0);
    if (w >= 14) asm volatile("s_waitcnt vmcnt(0)" ::: "memory");
    else         asm volatile("s_waitcnt vmcnt(4)" ::: "memory");
    __builtin_amdgcn_s_barrier();
  }
#undef STAGE_A
#undef STAGE_B

  // epilogue: bias + convert + scatter to Q/K/Vt layouts.
  #pragma unroll
  for (int nt = 0; nt < 4; ++nt){
    int col = col0 + wc * 64 + nt * 16 + l15;
    float bia = bias[col];
    int h = col >> 6, d = col & 63;
    #pragma unroll
    for (int mt = 0; mt < 8; ++mt){
      #pragma unroll
      for (int r = 0; r < 4; ++r){
        int mrow = row0 + wr * 128 + mt * 16 + lg * 4 + r;
        int b = mrow >> 11, n = mrow & 2047;
        float val = acc[mt][nt][r] + bia;
        if (v == 0){        // Q, scaled by 1/sqrt(D)=0.125 (exact in bf16)
          o0[((size_t)((b * 16 + h) * 2048 + n) << 6) + d] = f2bf(val * 0.125f);
        } else if (v == 1){ // K
          o1[((size_t)((b * 16 + h) * 2048 + n) << 6) + d] = f2bf(val);
        } else {            // V transposed: [b,h,d,n]
          o2[((size_t)((b * 16 + h) * 64 + d) << 11) + n] = f2bf(val);
        }
      }
    }
  }
}

// ---- causal flash attention, LDS-staged K/V shared by 4 waves of one head.
// Block = (head, 4 consecutive q-tiles). Per-wave math identical to the verified
// swapped-operand version: S^T = K.Q^T, lane-local online softmax (2 shfl/tile),
// P->bf16 via v_cvt_pk_bf16_f32 + v_permlane32_swap_b32, O^T = V^T.P^T.
// K/V tiles staged via global_load_lds with XOR-swizzled SOURCE address
// (linear LDS dest, rule: source perm == read perm), double-buffered.
template<int NKB, bool DIAG>
__device__ __forceinline__ void attn_tile_lds(
    const char* __restrict__ Kl, const char* __restrict__ Vl,
    int l31, int hi, int sw,
    const bf16x8* qf, float& m_, float& l_, f32x16& o0, f32x16& o1)
{
  // ---- K fragments from LDS (row = kpos, chunk = 2i+hi, swizzled by row&7)
  bf16x8 kf0[4], kf1[4];
  #pragma unroll
  for (int i = 0; i < 4; ++i)
    kf0[i] = *(const bf16x8*)(Kl + l31 * 128 + ((((2 * i + hi) << 4)) ^ sw));
  if (NKB == 2){
    #pragma unroll
    for (int i = 0; i < 4; ++i)
      kf1[i] = *(const bf16x8*)(Kl + (32 + l31) * 128 + ((((2 * i + hi) << 4)) ^ sw));
  }
  // ---- QK^T (S^T): s[kpos][q]
  f32x16 s0 = {}, s1 = {};
  #pragma unroll
  for (int i = 0; i < 4; ++i)
    s0 = __builtin_amdgcn_mfma_f32_32x32x16_bf16(kf0[i], qf[i], s0, 0, 0, 0);
  if (NKB == 2){
    #pragma unroll
    for (int i = 0; i < 4; ++i)
      s1 = __builtin_amdgcn_mfma_f32_32x32x16_bf16(kf1[i], qf[i], s1, 0, 0, 0);
  }
  // ---- V^T fragments from LDS (row = d, chunk = 2ks+hi)
  bf16x8 vf0[NKB * 2], vf1[NKB * 2];
  #pragma unroll
  for (int ks = 0; ks < NKB * 2; ++ks){
    vf0[ks] = *(const bf16x8*)(Vl + l31 * 128 + ((((2 * ks + hi) << 4)) ^ sw));
    vf1[ks] = *(const bf16x8*)(Vl + (32 + l31) * 128 + ((((2 * ks + hi) << 4)) ^ sw));
  }
  // ---- causal mask on the diagonal 32-block (always the last kblk)
  if (DIAG){
    const int hi4 = hi * 4;
    #pragma unroll
    for (int r = 0; r < 16; ++r){
      int kloc = (r & 3) + 8 * (r >> 2) + hi4;
      if (NKB == 1){ if (kloc > l31) s0[r] = -1e38f; }
      else         { if (kloc > l31) s1[r] = -1e38f; }
    }
  }
  // ---- online softmax, lane-local + one cross-half exchange
  float mloc = -1e38f;
  #pragma unroll
  for (int r = 0; r < 16; ++r){
    mloc = fmaxf(mloc, s0[r]);
    if (NKB == 2) mloc = fmaxf(mloc, s1[r]);
  }
  mloc = fmaxf(mloc, __shfl_xor(mloc, 32));
  const float mnew = fmaxf(m_, mloc);
  const float mc = mnew * LOG2E;
  const float corr = __builtin_amdgcn_exp2f(__builtin_fmaf(m_, LOG2E, -mc));
  m_ = mnew;
  float rs = 0.f;
  #pragma unroll
  for (int r = 0; r < 16; ++r){
    s0[r] = __builtin_amdgcn_exp2f(__builtin_fmaf(s0[r], LOG2E, -mc));
    rs += s0[r];
    if (NKB == 2){
      s1[r] = __builtin_amdgcn_exp2f(__builtin_fmaf(s1[r], LOG2E, -mc));
      rs += s1[r];
    }
  }
  rs += __shfl_xor(rs, 32);
  l_ = l_ * corr + rs;
  o0 *= corr; o1 *= corr;
  // ---- pack P to bf16 pairs: u0[c],u1[c] cover k = 8c+4hi+{0,1},{2,3}
  unsigned int u0[NKB * 4], u1[NKB * 4];
  #pragma unroll
  for (int c = 0; c < NKB * 4; ++c){
    const int b4 = (c & 3) * 4;
    float p0 = (c < 4) ? s0[b4]     : s1[b4];
    float p1 = (c < 4) ? s0[b4 + 1] : s1[b4 + 1];
    float p2 = (c < 4) ? s0[b4 + 2] : s1[b4 + 2];
    float p3 = (c < 4) ? s0[b4 + 3] : s1[b4 + 3];
    unsigned int w0, w1;
    asm("v_cvt_pk_bf16_f32 %0, %1, %2" : "=v"(w0) : "v"(p0), "v"(p1));
    asm("v_cvt_pk_bf16_f32 %0, %1, %2" : "=v"(w1) : "v"(p2), "v"(p3));
    u0[c] = w0; u1[c] = w1;
  }
  // ---- PV: O^T += V^T . P^T  (B-operand frag built via permlane32_swap)
  #pragma unroll
  for (int ks = 0; ks < NKB * 2; ++ks){
    unsigned int a0 = u0[2 * ks], b0 = u0[2 * ks + 1];
    unsigned int a1 = u1[2 * ks], b1 = u1[2 * ks + 1];
    asm("v_permlane32_swap_b32 %0, %1" : "+v"(a0), "+v"(b0));
    asm("v_permlane32_swap_b32 %0, %1" : "+v"(a1), "+v"(b1));
    union { unsigned int u[4]; bf16x8 v; } pa;
    pa.u[0] = a0; pa.u[1] = a1; pa.u[2] = b0; pa.u[3] = b1;
    o0 = __builtin_amdgcn_mfma_f32_32x32x16_bf16(vf0[ks], pa.v, o0, 0, 0, 0);
    o1 = __builtin_amdgcn_mfma_f32_32x32x16_bf16(vf1[ks], pa.v, o1, 0, 0, 0);
  }
}

__global__ __launch_bounds__(256) void attn(
    const unsigned short* __restrict__ Qg, const unsigned short* __restrict__ Kg,
    const unsigned short* __restrict__ Vt, float* __restrict__ out){
  // XCD-affinity mapping (assumes consecutive bids round-robin the 8 XCDs):
  // 8 heads per XCD -> per-XCD K+V working set 4 MB = L2 size.
  const int bid = blockIdx.x;                // 1024 blocks
  const int xcd = bid & 7, slot = bid >> 3;  // 128 slots per XCD
  const int head = xcd * 8 + (slot & 7);
  const int u = 15 - (slot >> 3);            // q-tile group, heavy-first
  const int wave = threadIdx.x >> 6, lane = threadIdx.x & 63;
  const int l31 = lane & 31, hi = lane >> 5;
  const int sw = (l31 & 7) << 4;             // read-side swizzle
  const int t = 4 * u + wave;                // this wave's q-tile
  const int q0 = t * 32;
  const int nfull = t >> 1;                  // full 64-wide KV tiles
  const bool odd = t & 1;
  const int ktmax = 2 * u + 1;               // last kt index for the block

  const unsigned short* qb = Qg + ((size_t)head << 17);
  const char* kbg = (const char*)(Kg + ((size_t)head << 17));
  const char* vbg = (const char*)(Vt + ((size_t)head << 17));

  __shared__ char Kl[2][8192];
  __shared__ char Vl[2][8192];

  bf16x8 qf[4];   // B-operand: col = q = lane&31, k-dim = 16i+8hi+j
  #pragma unroll
  for (int i = 0; i < 4; ++i)
    qf[i] = *(const bf16x8*)(qb + (size_t)(q0 + l31) * 64 + i * 16 + hi * 8);

  // staging: linear LDS dest, XOR-swizzled global source (perm == read perm).
  // per wave+round: 8 rows x 128B; lane covers row rows8+(lane>>3), chunk lane&7.
  const int csw = (((lane & 7) ^ (lane >> 3)) << 4) ;
  const int lrow = lane >> 3;
  #define STAGE(buf, kt) do {                                                   \
    _Pragma("unroll")                                                           \
    for (int r_ = 0; r_ < 2; ++r_){                                             \
      int rows8_ = (r_ * 4 + wave) * 8;                                         \
      int row_ = rows8_ + lrow;                                                 \
      gload_lds16(kbg + (size_t)((kt) * 64 + row_) * 128 + csw,                 \
                  Kl[buf] + (r_ * 4 + wave) * 1024);                            \
      gload_lds16(vbg + (size_t)row_ * 4096 + (size_t)(kt) * 128 + csw,         \
                  Vl[buf] + (r_ * 4 + wave) * 1024);                            \
    }                                                                           \
  } while (0)

  float m_ = -1e38f, l_ = 0.f;
  f32x16 o0 = {}, o1 = {};

  STAGE(0, 0);
  __syncthreads();
  int cur = 0;
  for (int kt = 0; kt <= ktmax; ++kt){
    if (kt < ktmax) STAGE(cur ^ 1, kt + 1);
    if (kt < nfull){
      attn_tile_lds<2, false>(Kl[cur], Vl[cur], l31, hi, sw, qf, m_, l_, o0, o1);
    } else if (kt == nfull){
      if (odd) attn_tile_lds<2, true>(Kl[cur], Vl[cur], l31, hi, sw, qf, m_, l_, o0, o1);
      else     attn_tile_lds<1, true>(Kl[cur], Vl[cur], l31, hi, sw, qf, m_, l_, o0, o1);
    }
    __syncthreads();
    cur ^= 1;
  }
  #undef STAGE

  // ---- epilogue: O^T[d][q] -> out[b, q, h*64+d], fp32
  const float inv = 1.f / l_;
  const int b = head >> 4, h = head & 15;
  float* op = out + ((size_t)(b * 2048 + q0 + l31) << 10) + h * 64 + hi * 4;
  #pragma unroll
  for (int c = 0; c < 4; ++c){
    *(float4*)(op + 8 * c) =
        make_float4(o0[4*c]*inv, o0[4*c+1]*inv, o0[4*c+2]*inv, o0[4*c+3]*inv);
    *(float4*)(op + 32 + 8 * c) =
        make_float4(o1[4*c]*inv, o1[4*c+1]*inv, o1[4*c+2]*inv, o1[4*c+3]*inv);
  }
}

extern "C" void kernel_launch(void* const* d_in, const int* in_sizes, int n_in,
                              void* d_out, int out_size, void* d_ws, size_t ws_size,
                              hipStream_t stream){
  const float* x  = (const float*)d_in[0];
  const float* Wq = (const float*)d_in[1];
  const float* bq = (const float*)d_in[2];
  const float* Wk = (const float*)d_in[3];
  const float* bk = (const float*)d_in[4];
  const float* Wv = (const float*)d_in[5];
  const float* bv = (const float*)d_in[6];
  float* out = (float*)d_out;
  char* ws = (char*)d_ws;
  // ws layout (bytes): xs 16MB | wtq/wtk/wtv 2MB each | Q 16MB | K 16MB | Vt 16MB = 70MB
  unsigned short* xs  = (unsigned short*)(ws);
  unsigned short* wtq = (unsigned short*)(ws + 16777216);
  unsigned short* wtk = (unsigned short*)(ws + 18874368);
  unsigned short* wtv = (unsigned short*)(ws + 20971520);
  unsigned short* Qg  = (unsigned short*)(ws + 23068672);
  unsigned short* Kg  = (unsigned short*)(ws + 39845888);
  unsigned short* Vt  = (unsigned short*)(ws + 56623104);

  cvt_x<<<4096, 256, 0, stream>>>(x, xs);
  cvt_w<<<dim3(512, 3), 256, 0, stream>>>(Wq, Wk, Wv, wtq, wtk, wtv);
  proj_gemm<<<dim3(32, 4, 3), 512, 0, stream>>>(xs, wtq, wtk, wtv, bq, bk, bv, Qg, Kg, Vt);
  attn<<<1024, 256, 0, stream>>>(Qg, Kg, Vt, out);
}